// Round 17
// baseline (183.606 us; speedup 1.0000x reference)
//
#include <hip/hip_runtime.h>

#define NHEAD 8
#define NQ 300
#define NBS 32
#define VTOT 8500
#define CDIM 256
#define NQS 75                        // 300/4 queries per wave-block
#define NBLKW (NBS * NHEAD * NQS)     // 19200 = 8 XCDs x 2400

// One WAVE per block, 4 queries end-to-end, plain C++ gathers (no asm).
// 32 independent wave-blocks/CU desync so GEMM-phase and gather-phase
// waves overlap on each CU.
__global__ __launch_bounds__(64, 8)
void msda_kernel(const float* __restrict__ query,
                 const float* __restrict__ refp,
                 const float* __restrict__ value,
                 const float* __restrict__ W_off,
                 const float* __restrict__ b_off,
                 const float* __restrict__ W_attn,
                 const float* __restrict__ b_attn,
                 float* __restrict__ out) {
    __shared__ float Aq[1040];        // 4 q-rows x 260 (padded); aliased by Pid/Pw
    __shared__ float S[200];          // 4q x 49 GEMM outputs
    __shared__ float Rp[16];          // 4q x 4 refpoints

    int4*   Pid = reinterpret_cast<int4*>(Aq);            // 64 int4 (floats 0..255)
    float4* Pw  = reinterpret_cast<float4*>(Aq + 256);    // 64 float4 (floats 256..511)

    const int lane = threadIdx.x;

    // Chunked XCD swizzle: pid%8 = XCD -> contiguous b-major chunk per XCD.
    const int pid = blockIdx.x;
    const int bid = (pid & 7) * (NBLKW / 8) + (pid >> 3);
    const int b   = bid / (NHEAD * NQS);
    const int r_  = bid - b * (NHEAD * NQS);
    const int h   = r_ / NQS;
    const int qs  = r_ - h * NQS;
    const int qw0 = qs * 4;           // rows qw0..qw0+3, always < 300

    // ---- phase 0: stage 4 query rows + refpoints ----
    #pragma unroll
    for (int i = 0; i < 4; ++i) {
        float4 v = *reinterpret_cast<const float4*>(
                       query + ((size_t)(b * NQ + qw0 + i) * CDIM + lane * 4));
        *reinterpret_cast<float4*>(&Aq[i * 260 + lane * 4]) = v;
    }
    if (lane < 16)
        Rp[lane] = refp[((size_t)(b * NQ + qw0 + (lane >> 2))) * 4 + (lane & 3)];
    __syncthreads();

    // ---- phase 1: GEMM 4q x 48 outputs; lane = (q, 4-col group), 48 active ----
    if (lane < 48) {
        const int q = lane / 12;
        const int g = lane - q * 12;
        const float* Wp;
        const float* bp;
        int stride, colbase, j;
        if (g < 8) {
            Wp = W_off;  bp = b_off;  stride = 256;
            colbase = h * 32 + 4 * g;  j = 4 * g;
        } else {
            Wp = W_attn; bp = b_attn; stride = 128;
            colbase = h * 16 + 4 * (g - 8); j = 32 + 4 * (g - 8);
        }
        float4 acc = *reinterpret_cast<const float4*>(bp + colbase);
        const float* a    = &Aq[q * 260];
        const float* wrow = Wp + colbase;
        #pragma unroll 2
        for (int k = 0; k < CDIM; k += 4) {
            float4 av = *reinterpret_cast<const float4*>(a + k);
            float4 w0 = *reinterpret_cast<const float4*>(wrow + (size_t)(k + 0) * stride);
            float4 w1 = *reinterpret_cast<const float4*>(wrow + (size_t)(k + 1) * stride);
            float4 w2 = *reinterpret_cast<const float4*>(wrow + (size_t)(k + 2) * stride);
            float4 w3 = *reinterpret_cast<const float4*>(wrow + (size_t)(k + 3) * stride);
            acc.x = fmaf(av.x, w0.x, acc.x); acc.y = fmaf(av.x, w0.y, acc.y);
            acc.z = fmaf(av.x, w0.z, acc.z); acc.w = fmaf(av.x, w0.w, acc.w);
            acc.x = fmaf(av.y, w1.x, acc.x); acc.y = fmaf(av.y, w1.y, acc.y);
            acc.z = fmaf(av.y, w1.z, acc.z); acc.w = fmaf(av.y, w1.w, acc.w);
            acc.x = fmaf(av.z, w2.x, acc.x); acc.y = fmaf(av.z, w2.y, acc.y);
            acc.z = fmaf(av.z, w2.z, acc.z); acc.w = fmaf(av.z, w2.w, acc.w);
            acc.x = fmaf(av.w, w3.x, acc.x); acc.y = fmaf(av.w, w3.y, acc.y);
            acc.z = fmaf(av.w, w3.z, acc.z); acc.w = fmaf(av.w, w3.w, acc.w);
        }
        S[q * 49 + j + 0] = acc.x;
        S[q * 49 + j + 1] = acc.y;
        S[q * 49 + j + 2] = acc.z;
        S[q * 49 + j + 3] = acc.w;
    }
    __syncthreads();

    // ---- phase 2: softmax + location + corner idx / premultiplied weights ----
    {
        const int q = lane >> 4;          // 0..3
        const int p = lane & 15;
        const float* Sq = &S[q * 49];

        float m = Sq[32];
        #pragma unroll
        for (int jj = 1; jj < 16; ++jj) m = fmaxf(m, Sq[32 + jj]);
        float ssum = 0.f;
        #pragma unroll
        for (int jj = 0; jj < 16; ++jj) ssum += __expf(Sq[32 + jj] - m);
        float aw = __expf(Sq[32 + p] - m) / ssum;

        float offx = Sq[2 * p], offy = Sq[2 * p + 1];
        float rx = Rp[q * 4 + 0], ry = Rp[q * 4 + 1];
        float rw = Rp[q * 4 + 2], rh = Rp[q * 4 + 3];
        float locx = rx + offx * 0.25f * rw * 0.5f;
        float locy = ry + offy * 0.25f * rh * 0.5f;

        int l  = p >> 2;
        int Wl = 80 >> l;
        int Hl = Wl;
        int base = (l > 0 ? 6400 : 0) + (l > 1 ? 1600 : 0) + (l > 2 ? 400 : 0);

        float x = locx * (float)Wl - 0.5f;
        float y = locy * (float)Hl - 0.5f;
        float x0f = floorf(x), y0f = floorf(y);
        float lx = x - x0f, ly = y - y0f;
        int x0 = (int)x0f, y0 = (int)y0f;
        int x1 = x0 + 1,   y1 = y0 + 1;

        bool vx0 = (x0 >= 0) && (x0 < Wl);
        bool vx1 = (x1 >= 0) && (x1 < Wl);
        bool vy0 = (y0 >= 0) && (y0 < Hl);
        bool vy1 = (y1 >= 0) && (y1 < Hl);
        int cx0 = min(max(x0, 0), Wl - 1), cx1 = min(max(x1, 0), Wl - 1);
        int cy0 = min(max(y0, 0), Hl - 1), cy1 = min(max(y1, 0), Hl - 1);

        float wx0 = 1.f - lx, wy0 = 1.f - ly;
        float w00 = wx0 * wy0 * aw * (float)(vx0 && vy0);
        float w10 = lx  * wy0 * aw * (float)(vx1 && vy0);
        float w01 = wx0 * ly  * aw * (float)(vx0 && vy1);
        float w11 = lx  * ly  * aw * (float)(vx1 && vy1);

        int s = (p + q) & 15;  // bank swizzle (matched by phase 3)
        Pid[q * 16 + s] = make_int4(base + cy0 * Wl + cx0, base + cy0 * Wl + cx1,
                                    base + cy1 * Wl + cx0, base + cy1 * Wl + cx1);
        Pw[q * 16 + s]  = make_float4(w00, w10, w01, w11);
    }
    __syncthreads();

    // ---- phase 3: fp32 dwordx4 gathers (plain C++, compiler-scheduled) ----
    {
        const int cp4 = lane & 3;         // 16B quad within the 64B half-slice
        const int ps  = (lane >> 2) & 3;  // 4-way p-split
        const int q   = lane >> 4;        // 0..3
        const float* vbase = value + (size_t)b * VTOT * CDIM + h * 32 + cp4 * 4;

        float a0 = 0.f, a1 = 0.f, a2 = 0.f, a3 = 0.f;   // channels cp4*4 ..
        float a4 = 0.f, a5 = 0.f, a6 = 0.f, a7 = 0.f;   // channels 16+cp4*4 ..

        #define ACC4(dv, wv, lo)                                         \
        {                                                                \
            if (lo) {                                                    \
                a0 = fmaf(wv, dv.x, a0); a1 = fmaf(wv, dv.y, a1);        \
                a2 = fmaf(wv, dv.z, a2); a3 = fmaf(wv, dv.w, a3);        \
            } else {                                                     \
                a4 = fmaf(wv, dv.x, a4); a5 = fmaf(wv, dv.y, a5);        \
                a6 = fmaf(wv, dv.z, a6); a7 = fmaf(wv, dv.w, a7);        \
            }                                                            \
        }

        #pragma unroll
        for (int j = 0; j < 4; ++j) {
            int p = ps + 4 * j;
            int s = (p + q) & 15;
            int4   id = Pid[q * 16 + s];
            float4 w  = Pw[q * 16 + s];
            const float* p0 = vbase + (size_t)id.x * CDIM;
            const float* p1 = vbase + (size_t)id.y * CDIM;
            const float* p2 = vbase + (size_t)id.z * CDIM;
            const float* p3 = vbase + (size_t)id.w * CDIM;
            float4 d0l = *reinterpret_cast<const float4*>(p0);
            float4 d0h = *reinterpret_cast<const float4*>(p0 + 16);
            float4 d1l = *reinterpret_cast<const float4*>(p1);
            float4 d1h = *reinterpret_cast<const float4*>(p1 + 16);
            float4 d2l = *reinterpret_cast<const float4*>(p2);
            float4 d2h = *reinterpret_cast<const float4*>(p2 + 16);
            float4 d3l = *reinterpret_cast<const float4*>(p3);
            float4 d3h = *reinterpret_cast<const float4*>(p3 + 16);
            ACC4(d0l, w.x, 1); ACC4(d0h, w.x, 0);
            ACC4(d1l, w.y, 1); ACC4(d1h, w.y, 0);
            ACC4(d2l, w.z, 1); ACC4(d2h, w.z, 0);
            ACC4(d3l, w.w, 1); ACC4(d3h, w.w, 0);
        }
        #undef ACC4

        // reduce over ps (lane bits 2,3 — stays within each q's 16-lane group)
        #pragma unroll
        for (int m = 4; m <= 8; m <<= 1) {
            a0 += __shfl_xor(a0, m, 64); a1 += __shfl_xor(a1, m, 64);
            a2 += __shfl_xor(a2, m, 64); a3 += __shfl_xor(a3, m, 64);
            a4 += __shfl_xor(a4, m, 64); a5 += __shfl_xor(a5, m, 64);
            a6 += __shfl_xor(a6, m, 64); a7 += __shfl_xor(a7, m, 64);
        }

        if (ps == 0) {
            int qg = qw0 + q;             // always < 300
            float* op = out + ((size_t)(b * NQ + qg)) * CDIM + h * 32;
            *reinterpret_cast<float4*>(op + cp4 * 4)      = make_float4(a0, a1, a2, a3);
            *reinterpret_cast<float4*>(op + 16 + cp4 * 4) = make_float4(a4, a5, a6, a7);
        }
    }
}

extern "C" void kernel_launch(void* const* d_in, const int* in_sizes, int n_in,
                              void* d_out, int out_size, void* d_ws, size_t ws_size,
                              hipStream_t stream) {
    const float* query  = (const float*)d_in[0];
    const float* refp   = (const float*)d_in[1];
    const float* value  = (const float*)d_in[2];
    const float* W_off  = (const float*)d_in[3];
    const float* b_off  = (const float*)d_in[4];
    const float* W_attn = (const float*)d_in[5];
    const float* b_attn = (const float*)d_in[6];
    float* out = (float*)d_out;

    msda_kernel<<<NBLKW, 64, 0, stream>>>(query, refp, value, W_off, b_off,
                                          W_attn, b_attn, out);
}

// Round 18
// 84.693 us; speedup vs baseline: 2.1679x; 2.1679x over previous
//
#include <hip/hip_runtime.h>

#define NHEAD 8
#define NQ 300
#define NBS 32
#define VTOT 8500
#define CDIM 256
#define TQ 16
#define NQT 19  // ceil(300/16)
#define NBLK (NBS * NHEAD * NQT)  // 4864 = 8 XCDs x 608

// Fused MSDA, fp32 gather; W staged through LDS in K-chunks (kills the
// 16x-redundant strided W streams that made phase 1 L2-latency-bound).
__global__ __launch_bounds__(256, 4)
void msda_kernel(const float* __restrict__ query,
                 const float* __restrict__ refp,
                 const float* __restrict__ value,
                 const float* __restrict__ W_off,
                 const float* __restrict__ b_off,
                 const float* __restrict__ W_attn,
                 const float* __restrict__ b_attn,
                 float* __restrict__ out) {
    __shared__ float Aq[TQ * 260];        // aliased by Pid/Pw after phase 1
    __shared__ float S[TQ * 49];
    __shared__ float Rp[TQ * 4];
    __shared__ float Wl[32 * 48];         // K-chunk of W: 32 rows x 48 cols (6 KB)

    int4*   Pid = reinterpret_cast<int4*>(Aq);            // 256 int4  = 4096 B
    float4* Pw  = reinterpret_cast<float4*>(Aq + 1024);   // 256 float4 = 4096 B

    const int tid = threadIdx.x;
    // Chunked XCD swizzle: pid%8 = XCD -> contiguous b-major chunk per XCD.
    const int pid = blockIdx.x;
    const int bid = (pid & 7) * (NBLK / 8) + (pid >> 3);
    const int b   = bid / (NHEAD * NQT);
    const int r_  = bid - b * (NHEAD * NQT);
    const int h   = r_ / NQT;
    const int qt  = r_ - h * NQT;
    const int q0  = qt * TQ;

    // ---- phase 0: stage query tile + reference points ----
    #pragma unroll
    for (int i = 0; i < 4; ++i) {
        int f4 = i * 256 + tid;
        int q  = f4 >> 6;
        int kk = (f4 & 63) << 2;
        float4 v = make_float4(0.f, 0.f, 0.f, 0.f);
        if (q0 + q < NQ)
            v = *reinterpret_cast<const float4*>(
                    query + ((size_t)(b * NQ + q0 + q) * CDIM + kk));
        *reinterpret_cast<float4*>(&Aq[q * 260 + kk]) = v;
    }
    if (tid < TQ * 4) {
        int q = tid >> 2, c = tid & 3;
        Rp[tid] = (q0 + q < NQ) ? refp[((size_t)(b * NQ + q0 + q)) * 4 + c] : 0.5f;
    }
    __syncthreads();

    // ---- phase 1: GEMM 16q x 48 outputs, W staged via LDS in chunks of 32 k ----
    {
        const int q = (tid < 192) ? tid / 12 : 0;
        const int g = (tid < 192) ? tid - q * 12 : 0;
        const int j = (g < 8) ? 4 * g : 32 + 4 * (g - 8);   // Wl col == output idx
        float4 acc;
        if (tid < 192) {
            const float* bp = (g < 8) ? (b_off + h * 32 + 4 * g)
                                      : (b_attn + h * 16 + 4 * (g - 8));
            acc = *reinterpret_cast<const float4*>(bp);
        } else {
            acc = make_float4(0.f, 0.f, 0.f, 0.f);
        }

        for (int kk = 0; kk < CDIM; kk += 32) {
            // stage 32 rows x 48 cols = 384 float4 tasks, coalesced full lines
            #pragma unroll
            for (int t = tid; t < 384; t += 256) {
                int r  = t / 12;
                int fi = t - r * 12;
                const float* src = (fi < 8)
                    ? (W_off  + (size_t)(kk + r) * 256 + h * 32 + fi * 4)
                    : (W_attn + (size_t)(kk + r) * 128 + h * 16 + (fi - 8) * 4);
                *reinterpret_cast<float4*>(&Wl[r * 48 + fi * 4]) =
                    *reinterpret_cast<const float4*>(src);
            }
            __syncthreads();

            if (tid < 192) {
                const float* a = &Aq[q * 260 + kk];
                #pragma unroll
                for (int k = 0; k < 32; k += 4) {
                    float4 av = *reinterpret_cast<const float4*>(a + k);
                    float4 w0 = *reinterpret_cast<const float4*>(&Wl[(k + 0) * 48 + j]);
                    float4 w1 = *reinterpret_cast<const float4*>(&Wl[(k + 1) * 48 + j]);
                    float4 w2 = *reinterpret_cast<const float4*>(&Wl[(k + 2) * 48 + j]);
                    float4 w3 = *reinterpret_cast<const float4*>(&Wl[(k + 3) * 48 + j]);
                    acc.x = fmaf(av.x, w0.x, acc.x); acc.y = fmaf(av.x, w0.y, acc.y);
                    acc.z = fmaf(av.x, w0.z, acc.z); acc.w = fmaf(av.x, w0.w, acc.w);
                    acc.x = fmaf(av.y, w1.x, acc.x); acc.y = fmaf(av.y, w1.y, acc.y);
                    acc.z = fmaf(av.y, w1.z, acc.z); acc.w = fmaf(av.y, w1.w, acc.w);
                    acc.x = fmaf(av.z, w2.x, acc.x); acc.y = fmaf(av.z, w2.y, acc.y);
                    acc.z = fmaf(av.z, w2.z, acc.z); acc.w = fmaf(av.z, w2.w, acc.w);
                    acc.x = fmaf(av.w, w3.x, acc.x); acc.y = fmaf(av.w, w3.y, acc.y);
                    acc.z = fmaf(av.w, w3.z, acc.z); acc.w = fmaf(av.w, w3.w, acc.w);
                }
            }
            __syncthreads();
        }

        if (tid < 192) {
            S[q * 49 + j + 0] = acc.x;
            S[q * 49 + j + 1] = acc.y;
            S[q * 49 + j + 2] = acc.z;
            S[q * 49 + j + 3] = acc.w;
        }
    }
    __syncthreads();

    // ---- phase 2: softmax + location + corner idx / premultiplied weights ----
    {
        const int q = tid >> 4;
        const int p = tid & 15;
        const float* Sq = &S[q * 49];

        float m = Sq[32];
        #pragma unroll
        for (int jj = 1; jj < 16; ++jj) m = fmaxf(m, Sq[32 + jj]);
        float ssum = 0.f;
        #pragma unroll
        for (int jj = 0; jj < 16; ++jj) ssum += __expf(Sq[32 + jj] - m);
        float aw = __expf(Sq[32 + p] - m) / ssum;

        float offx = Sq[2 * p], offy = Sq[2 * p + 1];
        float rx = Rp[q * 4 + 0], ry = Rp[q * 4 + 1];
        float rw = Rp[q * 4 + 2], rh = Rp[q * 4 + 3];
        float locx = rx + offx * 0.25f * rw * 0.5f;
        float locy = ry + offy * 0.25f * rh * 0.5f;

        int l  = p >> 2;
        int Wd = 80 >> l;
        int base = (l > 0 ? 6400 : 0) + (l > 1 ? 1600 : 0) + (l > 2 ? 400 : 0);

        float x = locx * (float)Wd - 0.5f;
        float y = locy * (float)Wd - 0.5f;
        float x0f = floorf(x), y0f = floorf(y);
        float lx = x - x0f, ly = y - y0f;
        int x0 = (int)x0f, y0 = (int)y0f;
        int x1 = x0 + 1,   y1 = y0 + 1;

        bool vx0 = (x0 >= 0) && (x0 < Wd);
        bool vx1 = (x1 >= 0) && (x1 < Wd);
        bool vy0 = (y0 >= 0) && (y0 < Wd);
        bool vy1 = (y1 >= 0) && (y1 < Wd);
        int cx0 = min(max(x0, 0), Wd - 1), cx1 = min(max(x1, 0), Wd - 1);
        int cy0 = min(max(y0, 0), Wd - 1), cy1 = min(max(y1, 0), Wd - 1);

        float wx0 = 1.f - lx, wy0 = 1.f - ly;
        float w00 = wx0 * wy0 * aw * (float)(vx0 && vy0);
        float w10 = lx  * wy0 * aw * (float)(vx1 && vy0);
        float w01 = wx0 * ly  * aw * (float)(vx0 && vy1);
        float w11 = lx  * ly  * aw * (float)(vx1 && vy1);

        int s = (p + q) & 15;  // bank swizzle (matched by phase 3)
        Pid[q * 16 + s] = make_int4(base + cy0 * Wd + cx0, base + cy0 * Wd + cx1,
                                    base + cy1 * Wd + cx0, base + cy1 * Wd + cx1);
        Pw[q * 16 + s]  = make_float4(w00, w10, w01, w11);
    }
    __syncthreads();

    // ---- phase 3: fp32 dwordx4 gathers (plain C++, compiler-scheduled) ----
    {
        const int cp4 = tid & 3;          // 16B quad within the 64B half-slice
        const int ps  = (tid >> 2) & 3;   // 4-way p-split
        const int q   = tid >> 4;         // 16 q
        const float* vbase = value + (size_t)b * VTOT * CDIM + h * 32 + cp4 * 4;

        float a0 = 0.f, a1 = 0.f, a2 = 0.f, a3 = 0.f;
        float a4 = 0.f, a5 = 0.f, a6 = 0.f, a7 = 0.f;

        #define ACC4(dv, wv, lo)                                         \
        {                                                                \
            if (lo) {                                                    \
                a0 = fmaf(wv, dv.x, a0); a1 = fmaf(wv, dv.y, a1);        \
                a2 = fmaf(wv, dv.z, a2); a3 = fmaf(wv, dv.w, a3);        \
            } else {                                                     \
                a4 = fmaf(wv, dv.x, a4); a5 = fmaf(wv, dv.y, a5);        \
                a6 = fmaf(wv, dv.z, a6); a7 = fmaf(wv, dv.w, a7);        \
            }                                                            \
        }

        #pragma unroll
        for (int jj = 0; jj < 4; ++jj) {
            int p = ps + 4 * jj;
            int s = (p + q) & 15;
            int4   id = Pid[q * 16 + s];
            float4 w  = Pw[q * 16 + s];
            const float* p0 = vbase + (size_t)id.x * CDIM;
            const float* p1 = vbase + (size_t)id.y * CDIM;
            const float* p2 = vbase + (size_t)id.z * CDIM;
            const float* p3 = vbase + (size_t)id.w * CDIM;
            float4 d0l = *reinterpret_cast<const float4*>(p0);
            float4 d0h = *reinterpret_cast<const float4*>(p0 + 16);
            float4 d1l = *reinterpret_cast<const float4*>(p1);
            float4 d1h = *reinterpret_cast<const float4*>(p1 + 16);
            float4 d2l = *reinterpret_cast<const float4*>(p2);
            float4 d2h = *reinterpret_cast<const float4*>(p2 + 16);
            float4 d3l = *reinterpret_cast<const float4*>(p3);
            float4 d3h = *reinterpret_cast<const float4*>(p3 + 16);
            ACC4(d0l, w.x, 1); ACC4(d0h, w.x, 0);
            ACC4(d1l, w.y, 1); ACC4(d1h, w.y, 0);
            ACC4(d2l, w.z, 1); ACC4(d2h, w.z, 0);
            ACC4(d3l, w.w, 1); ACC4(d3h, w.w, 0);
        }
        #undef ACC4

        // reduce over ps (lane bits 2,3)
        #pragma unroll
        for (int m = 4; m <= 8; m <<= 1) {
            a0 += __shfl_xor(a0, m, 64); a1 += __shfl_xor(a1, m, 64);
            a2 += __shfl_xor(a2, m, 64); a3 += __shfl_xor(a3, m, 64);
            a4 += __shfl_xor(a4, m, 64); a5 += __shfl_xor(a5, m, 64);
            a6 += __shfl_xor(a6, m, 64); a7 += __shfl_xor(a7, m, 64);
        }

        int qg = q0 + q;
        if (ps == 0 && qg < NQ) {
            float* op = out + ((size_t)(b * NQ + qg)) * CDIM + h * 32;
            *reinterpret_cast<float4*>(op + cp4 * 4)      = make_float4(a0, a1, a2, a3);
            *reinterpret_cast<float4*>(op + 16 + cp4 * 4) = make_float4(a4, a5, a6, a7);
        }
    }
}

extern "C" void kernel_launch(void* const* d_in, const int* in_sizes, int n_in,
                              void* d_out, int out_size, void* d_ws, size_t ws_size,
                              hipStream_t stream) {
    const float* query  = (const float*)d_in[0];
    const float* refp   = (const float*)d_in[1];
    const float* value  = (const float*)d_in[2];
    const float* W_off  = (const float*)d_in[3];
    const float* b_off  = (const float*)d_in[4];
    const float* W_attn = (const float*)d_in[5];
    const float* b_attn = (const float*)d_in[6];
    float* out = (float*)d_out;

    msda_kernel<<<NBLK, 256, 0, stream>>>(query, refp, value, W_off, b_off,
                                          W_attn, b_attn, out);
}